// Round 1
// baseline (355.921 us; speedup 1.0000x reference)
//
#include <hip/hip_runtime.h>

#define NUM_F 39
#define NUM_P 741      // 39*38/2
#define DIM   64

__global__ __launch_bounds__(256, 1) void afm_fused(
    const int*   __restrict__ feat_index,   // [B, F]
    const float* __restrict__ feat_value,   // [B, F]
    const float* __restrict__ fo_w,         // [NUM_FEATS, 1]
    const float* __restrict__ emb_table,    // [NUM_FEATS, 64]
    const float* __restrict__ att_W,        // [64, 64] (d, a) row-major
    const float* __restrict__ att_b,        // [64]
    const float* __restrict__ att_h,        // [64]
    const float* __restrict__ p_vec,        // [64]
    const float* __restrict__ bias,         // [1]
    float*       __restrict__ out)          // [B]
{
    const int b = blockIdx.x;
    const int t = threadIdx.x;

    __shared__ float e_lds[NUM_F][68];           // padded (68) to break e-read bank conflicts
    __shared__ float W_lds[DIM * DIM];           // same layout as att_W: [d][a]
    __shared__ float b_lds[DIM], h_lds[DIM], pv_lds[DIM];
    __shared__ float red[256], redq[256];
    __shared__ unsigned char rowA[NUM_P], colA[NUM_P];
    __shared__ int   s_idx[NUM_F];
    __shared__ float s_fv[NUM_F];
    __shared__ float s_yfirst;

    // ---- stage: indices, values, small vectors, pair map, W ----
    if (t < NUM_F) {
        s_idx[t] = feat_index[b * NUM_F + t];
        s_fv[t]  = feat_value[b * NUM_F + t];
    }
    if (t < DIM) {
        b_lds[t]  = att_b[t];
        h_lds[t]  = att_h[t];
        pv_lds[t] = p_vec[t];
    }
    if (t < NUM_F) {   // build triu(k=1) pair map, row-major (matches np.triu_indices)
        int r = t;
        int off = r * (2 * NUM_F - r - 1) / 2;
        for (int c = r + 1; c < NUM_F; ++c) {
            rowA[off] = (unsigned char)r;
            colA[off] = (unsigned char)c;
            ++off;
        }
    }
    {   // W: coalesced float4 copy (16 KB)
        const float4* src = (const float4*)att_W;
        float4*       dst = (float4*)W_lds;
        for (int q = t; q < DIM * DIM / 4; q += 256) dst[q] = src[q];
    }
    __syncthreads();

    // ---- y_first partials + embedding staging (both need s_idx/s_fv) ----
    float yf = 0.f;
    if (t < NUM_F) yf = fo_w[s_idx[t]] * s_fv[t];
    red[t] = yf;

    {
        const float4* emb4 = (const float4*)emb_table;
        for (int q = t; q < NUM_F * 16; q += 256) {
            int f  = q >> 4;
            int d4 = q & 15;
            float4 v = emb4[(size_t)s_idx[f] * 16 + d4];
            float fv = s_fv[f];
            v.x *= fv; v.y *= fv; v.z *= fv; v.w *= fv;
            *(float4*)&e_lds[f][d4 * 4] = v;
        }
    }
    __syncthreads();

    // reduce y_first
    for (int s = 128; s > 0; s >>= 1) {
        if (t < s) red[t] += red[t + s];
        __syncthreads();
    }
    if (t == 0) s_yfirst = red[0];
    __syncthreads();   // also protects red[] reuse below

    // ---- pair sweeps: each thread owns pairs t, t+256, t+512 ----
    float sigv[3], qv[3];
    #pragma unroll
    for (int it = 0; it < 3; ++it) { sigv[it] = -1e30f; qv[it] = 0.f; }

    #pragma unroll 1
    for (int it = 0; it < 3; ++it) {
        const int p = t + it * 256;
        if (p < NUM_P) {
            const int r = (int)rowA[p];
            const int c = (int)colA[p];

            float inter[DIM];
            #pragma unroll
            for (int d4 = 0; d4 < 16; ++d4) {
                float4 er = *(const float4*)&e_lds[r][d4 * 4];
                float4 ec = *(const float4*)&e_lds[c][d4 * 4];
                inter[d4 * 4 + 0] = er.x * ec.x;
                inter[d4 * 4 + 1] = er.y * ec.y;
                inter[d4 * 4 + 2] = er.z * ec.z;
                inter[d4 * 4 + 3] = er.w * ec.w;
            }

            // q[p] = inter . p_vec
            float qq = 0.f;
            #pragma unroll
            for (int d4 = 0; d4 < 16; ++d4) {
                float4 pv = *(const float4*)&pv_lds[d4 * 4];
                qq += inter[d4*4+0] * pv.x + inter[d4*4+1] * pv.y
                    + inter[d4*4+2] * pv.z + inter[d4*4+3] * pv.w;
            }

            // sig[p] = sum_a relu(b[a] + sum_d inter[d] W[d][a]) * h[a]
            float ss = 0.f;
            #pragma unroll 1
            for (int a4 = 0; a4 < 16; ++a4) {
                const float4 bb = *(const float4*)&b_lds[a4 * 4];
                float z0 = bb.x, z1 = bb.y, z2 = bb.z, z3 = bb.w;
                #pragma unroll
                for (int d = 0; d < DIM; ++d) {
                    // wave-uniform address -> LDS broadcast read
                    float4 w = *(const float4*)&W_lds[d * DIM + a4 * 4];
                    z0 += inter[d] * w.x;
                    z1 += inter[d] * w.y;
                    z2 += inter[d] * w.z;
                    z3 += inter[d] * w.w;
                }
                const float4 hh = *(const float4*)&h_lds[a4 * 4];
                ss += fmaxf(z0, 0.f) * hh.x + fmaxf(z1, 0.f) * hh.y
                    + fmaxf(z2, 0.f) * hh.z + fmaxf(z3, 0.f) * hh.w;
            }
            sigv[it] = ss;
            qv[it]   = qq;
        }
    }

    // ---- softmax over 741 logits + attention pooling (scalar form) ----
    float m = -1e30f;
    #pragma unroll
    for (int i = 0; i < 3; ++i) m = fmaxf(m, sigv[i]);
    red[t] = m;
    __syncthreads();
    for (int s = 128; s > 0; s >>= 1) {
        if (t < s) red[t] = fmaxf(red[t], red[t + s]);
        __syncthreads();
    }
    const float M = red[0];
    __syncthreads();   // before reusing red

    float S = 0.f, Q = 0.f;
    #pragma unroll
    for (int i = 0; i < 3; ++i) {
        float eo = __expf(sigv[i] - M);   // invalid slots: exp(-huge) -> 0
        S += eo;
        Q += eo * qv[i];
    }
    red[t] = S; redq[t] = Q;
    __syncthreads();
    for (int s = 128; s > 0; s >>= 1) {
        if (t < s) { red[t] += red[t + s]; redq[t] += redq[t + s]; }
        __syncthreads();
    }

    if (t == 0) {
        const float att_pool = redq[0] / red[0];
        const float x = bias[0] + s_yfirst + att_pool;
        out[b] = 1.f / (1.f + __expf(-x));
    }
}

extern "C" void kernel_launch(void* const* d_in, const int* in_sizes, int n_in,
                              void* d_out, int out_size, void* d_ws, size_t ws_size,
                              hipStream_t stream) {
    const int*   feat_index = (const int*)  d_in[0];
    const float* feat_value = (const float*)d_in[1];
    const float* fo_w       = (const float*)d_in[2];
    const float* emb_table  = (const float*)d_in[3];
    const float* att_W      = (const float*)d_in[4];
    const float* att_b      = (const float*)d_in[5];
    const float* att_h      = (const float*)d_in[6];
    const float* p_vec      = (const float*)d_in[7];
    const float* bias       = (const float*)d_in[8];
    float*       out        = (float*)d_out;

    const int B = in_sizes[0] / NUM_F;   // 2048

    afm_fused<<<B, 256, 0, stream>>>(feat_index, feat_value, fo_w, emb_table,
                                     att_W, att_b, att_h, p_vec, bias, out);
}

// Round 2
// 49.025 us; speedup vs baseline: 7.2599x; 7.2599x over previous
//
#include <hip/hip_runtime.h>
#include <hip/hip_bf16.h>

#define NUM_F  39
#define NUM_P  741      // 39*38/2
#define NPAD   752      // 47 tiles * 16
#define DIM    64
#define NTILES 47
#define ESTR   68       // padded fp32 row stride for E

typedef float f32x4 __attribute__((ext_vector_type(4)));
typedef short s16x8 __attribute__((ext_vector_type(8)));

static __device__ __forceinline__ unsigned short f2bf(float x) {
    unsigned int u = __float_as_uint(x);
    u += 0x7FFF + ((u >> 16) & 1);     // RNE
    return (unsigned short)(u >> 16);
}

union PackAB {
    s16x8 v;
    __hip_bfloat162 h[4];
    unsigned short u[8];
};

__global__ __launch_bounds__(256, 2) void afm_mfma(
    const int*   __restrict__ feat_index,   // [B, F]
    const float* __restrict__ feat_value,   // [B, F]
    const float* __restrict__ fo_w,         // [NUM_FEATS, 1]
    const float* __restrict__ emb_table,    // [NUM_FEATS, 64]
    const float* __restrict__ att_W,        // [64, 64] (d, a)
    const float* __restrict__ att_b,        // [64]
    const float* __restrict__ att_h,        // [64]
    const float* __restrict__ p_vec,        // [64]
    const float* __restrict__ bias,         // [1]
    float*       __restrict__ out)          // [B]
{
    const int b    = blockIdx.x;
    const int t    = threadIdx.x;
    const int wave = t >> 6;
    const int lane = t & 63;
    const int la   = lane & 15;   // A row / B,C col within tile
    const int lg   = lane >> 4;   // k-group

    __shared__ float          e_lds[NUM_F][ESTR];   // scaled embeddings, fp32
    __shared__ unsigned short Wt[DIM][72];          // W^T in bf16: Wt[a][d], padded
    __shared__ float          sig_s[NPAD];
    __shared__ float          q_s[NPAD];
    __shared__ float          pv_lds[DIM];
    __shared__ float          red[256], redq[256];
    __shared__ unsigned char  rowA[NPAD], colA[NPAD];
    __shared__ int            s_idx[NUM_F];
    __shared__ float          s_fv[NUM_F];
    __shared__ float          s_yfirst;

    // ---------------- phase 0: staging (pre-barrier) ----------------
    int   my_idx = 0;
    float my_fv  = 0.f;
    if (t < NUM_F) {
        my_idx   = feat_index[b * NUM_F + t];
        my_fv    = feat_value[b * NUM_F + t];
        s_idx[t] = my_idx;
        s_fv[t]  = my_fv;
    }
    if (t < DIM) pv_lds[t] = p_vec[t];
    if (t < NUM_F) {   // triu(k=1) pair map, row-major
        int r = t, off = r * (2 * NUM_F - r - 1) / 2;
        for (int c = r + 1; c < NUM_F; ++c) { rowA[off] = (unsigned char)r; colA[off] = (unsigned char)c; ++off; }
    }
    if (t < NPAD - NUM_P) { rowA[NUM_P + t] = 0; colA[NUM_P + t] = 0; }   // pad tail

    // W^T -> bf16 LDS (coalesced reads, one-time scattered writes)
    for (int q = t; q < DIM * DIM; q += 256) {
        int d = q >> 6, a = q & 63;
        Wt[a][d] = f2bf(att_W[q]);
    }

    // y_first: wave 0 only (lanes 0..38 hold values), butterfly reduce
    float yf = (t < NUM_F) ? fo_w[my_idx] * my_fv : 0.f;
    if (wave == 0) {
        #pragma unroll
        for (int m = 1; m < 64; m <<= 1) yf += __shfl_xor(yf, m);
        if (t == 0) s_yfirst = yf;
    }
    __syncthreads();

    // ---------------- phase 1: E staging + loop-invariant frags ----------------
    {
        const float4* emb4 = (const float4*)emb_table;
        for (int q = t; q < NUM_F * 16; q += 256) {
            int f = q >> 4, d4 = q & 15;
            float4 v = emb4[(size_t)s_idx[f] * 16 + d4];
            float fv = s_fv[f];
            v.x *= fv; v.y *= fv; v.z *= fv; v.w *= fv;
            *(float4*)&e_lds[f][d4 * 4] = v;
        }
    }

    // B-frags: Bf[n][kf] lane holds col a = n*16+la, k = kf*32 + lg*8 + j (j=0..7)
    s16x8 Bf[4][2];
    #pragma unroll
    for (int n = 0; n < 4; ++n)
        #pragma unroll
        for (int kf = 0; kf < 2; ++kf)
            Bf[n][kf] = *(const s16x8*)&Wt[n * 16 + la][kf * 32 + lg * 8];

    // p_vec as a single B column (col 0 of a 5th N-tile) -> q via MFMA
    s16x8 Bq[2];
    #pragma unroll
    for (int kf = 0; kf < 2; ++kf) {
        PackAB P;
        #pragma unroll
        for (int j = 0; j < 8; ++j) {
            float x = (la == 0) ? pv_lds[kf * 32 + lg * 8 + j] : 0.f;
            P.u[j] = f2bf(x);
        }
        Bq[kf] = P.v;
    }

    const float bn0 = att_b[la],      bn1 = att_b[16 + la];
    const float bn2 = att_b[32 + la], bn3 = att_b[48 + la];
    const float hn0 = att_h[la],      hn1 = att_h[16 + la];
    const float hn2 = att_h[32 + la], hn3 = att_h[48 + la];
    __syncthreads();

    // ---------------- phase 2: pair-tile loop (16 pairs / tile / wave) ----------------
    for (int tile = wave; tile < NTILES; tile += 4) {
        const int p0 = tile << 4;
        const int p  = p0 + la;
        const int r  = rowA[p];
        const int c  = colA[p];

        const float* er = &e_lds[r][lg * 8];
        const float* ec = &e_lds[c][lg * 8];
        float4 ra0 = *(const float4*)(er);
        float4 ra1 = *(const float4*)(er + 4);
        float4 rb0 = *(const float4*)(er + 32);
        float4 rb1 = *(const float4*)(er + 36);
        float4 ca0 = *(const float4*)(ec);
        float4 ca1 = *(const float4*)(ec + 4);
        float4 cb0 = *(const float4*)(ec + 32);
        float4 cb1 = *(const float4*)(ec + 36);

        PackAB A0, A1;   // A row = la, k = lg*8+j (A0: k 0..31, A1: k 32..63)
        A0.h[0] = __float22bfloat162_rn(make_float2(ra0.x * ca0.x, ra0.y * ca0.y));
        A0.h[1] = __float22bfloat162_rn(make_float2(ra0.z * ca0.z, ra0.w * ca0.w));
        A0.h[2] = __float22bfloat162_rn(make_float2(ra1.x * ca1.x, ra1.y * ca1.y));
        A0.h[3] = __float22bfloat162_rn(make_float2(ra1.z * ca1.z, ra1.w * ca1.w));
        A1.h[0] = __float22bfloat162_rn(make_float2(rb0.x * cb0.x, rb0.y * cb0.y));
        A1.h[1] = __float22bfloat162_rn(make_float2(rb0.z * cb0.z, rb0.w * cb0.w));
        A1.h[2] = __float22bfloat162_rn(make_float2(rb1.x * cb1.x, rb1.y * cb1.y));
        A1.h[3] = __float22bfloat162_rn(make_float2(rb1.z * cb1.z, rb1.w * cb1.w));

        // att_b folded into accumulator init (b depends only on col)
        f32x4 a0 = {bn0, bn0, bn0, bn0};
        f32x4 a1 = {bn1, bn1, bn1, bn1};
        f32x4 a2 = {bn2, bn2, bn2, bn2};
        f32x4 a3 = {bn3, bn3, bn3, bn3};
        f32x4 aq = {0.f, 0.f, 0.f, 0.f};

        a0 = __builtin_amdgcn_mfma_f32_16x16x32_bf16(A0.v, Bf[0][0], a0, 0, 0, 0);
        a0 = __builtin_amdgcn_mfma_f32_16x16x32_bf16(A1.v, Bf[0][1], a0, 0, 0, 0);
        a1 = __builtin_amdgcn_mfma_f32_16x16x32_bf16(A0.v, Bf[1][0], a1, 0, 0, 0);
        a1 = __builtin_amdgcn_mfma_f32_16x16x32_bf16(A1.v, Bf[1][1], a1, 0, 0, 0);
        a2 = __builtin_amdgcn_mfma_f32_16x16x32_bf16(A0.v, Bf[2][0], a2, 0, 0, 0);
        a2 = __builtin_amdgcn_mfma_f32_16x16x32_bf16(A1.v, Bf[2][1], a2, 0, 0, 0);
        a3 = __builtin_amdgcn_mfma_f32_16x16x32_bf16(A0.v, Bf[3][0], a3, 0, 0, 0);
        a3 = __builtin_amdgcn_mfma_f32_16x16x32_bf16(A1.v, Bf[3][1], a3, 0, 0, 0);
        aq = __builtin_amdgcn_mfma_f32_16x16x32_bf16(A0.v, Bq[0],    aq, 0, 0, 0);
        aq = __builtin_amdgcn_mfma_f32_16x16x32_bf16(A1.v, Bq[1],    aq, 0, 0, 0);

        // epilogue: sig row-sums. C layout: col = n*16+la, row = p0 + lg*4 + reg
        #define RS(i) fmaf(fmaxf(a3[i], 0.f), hn3, fmaf(fmaxf(a2[i], 0.f), hn2, \
                      fmaf(fmaxf(a1[i], 0.f), hn1, fmaxf(a0[i], 0.f) * hn0)))
        float l0 = RS(0), l1 = RS(1), l2 = RS(2), l3 = RS(3);
        #undef RS

        #pragma unroll
        for (int m = 1; m <= 8; m <<= 1) {   // reduce over the 16 cols (la dim)
            l0 += __shfl_xor(l0, m);
            l1 += __shfl_xor(l1, m);
            l2 += __shfl_xor(l2, m);
            l3 += __shfl_xor(l3, m);
        }

        const int rb = p0 + (lg << 2);
        if (la == 0 && rb     < NUM_P) sig_s[rb]     = l0;
        if (la == 1 && rb + 1 < NUM_P) sig_s[rb + 1] = l1;
        if (la == 2 && rb + 2 < NUM_P) sig_s[rb + 2] = l2;
        if (la == 3 && rb + 3 < NUM_P) sig_s[rb + 3] = l3;
        if (la == 0) {   // q lives in col 0 of the aq tile
            if (rb     < NUM_P) q_s[rb]     = aq[0];
            if (rb + 1 < NUM_P) q_s[rb + 1] = aq[1];
            if (rb + 2 < NUM_P) q_s[rb + 2] = aq[2];
            if (rb + 3 < NUM_P) q_s[rb + 3] = aq[3];
        }
    }
    __syncthreads();

    // ---------------- phase 3: softmax + pooling ----------------
    float sv[3], qv[3];
    #pragma unroll
    for (int i = 0; i < 3; ++i) {
        int p = t + i * 256;
        bool ok = p < NUM_P;
        sv[i] = ok ? sig_s[p] : -1e30f;
        qv[i] = ok ? q_s[p]   : 0.f;
    }

    float m = fmaxf(fmaxf(sv[0], sv[1]), sv[2]);
    red[t] = m;
    __syncthreads();
    for (int s = 128; s > 0; s >>= 1) {
        if (t < s) red[t] = fmaxf(red[t], red[t + s]);
        __syncthreads();
    }
    const float M = red[0];
    __syncthreads();

    float S = 0.f, Q = 0.f;
    #pragma unroll
    for (int i = 0; i < 3; ++i) {
        float eo = __expf(sv[i] - M);
        S += eo;
        Q += eo * qv[i];
    }
    red[t] = S; redq[t] = Q;
    __syncthreads();
    for (int s = 128; s > 0; s >>= 1) {
        if (t < s) { red[t] += red[t + s]; redq[t] += redq[t + s]; }
        __syncthreads();
    }

    if (t == 0) {
        const float att_pool = redq[0] / red[0];
        const float x = bias[0] + s_yfirst + att_pool;
        out[b] = 1.f / (1.f + __expf(-x));
    }
}

extern "C" void kernel_launch(void* const* d_in, const int* in_sizes, int n_in,
                              void* d_out, int out_size, void* d_ws, size_t ws_size,
                              hipStream_t stream) {
    const int*   feat_index = (const int*)  d_in[0];
    const float* feat_value = (const float*)d_in[1];
    const float* fo_w       = (const float*)d_in[2];
    const float* emb_table  = (const float*)d_in[3];
    const float* att_W      = (const float*)d_in[4];
    const float* att_b      = (const float*)d_in[5];
    const float* att_h      = (const float*)d_in[6];
    const float* p_vec      = (const float*)d_in[7];
    const float* bias       = (const float*)d_in[8];
    float*       out        = (float*)d_out;

    const int B = in_sizes[0] / NUM_F;   // 2048

    afm_mfma<<<B, 256, 0, stream>>>(feat_index, feat_value, fo_w, emb_table,
                                    att_W, att_b, att_h, p_vec, bias, out);
}

// Round 3
// 31.724 us; speedup vs baseline: 11.2192x; 1.5454x over previous
//
#include <hip/hip_runtime.h>
#include <hip/hip_fp16.h>

#define NUM_F  39
#define NUM_P  741      // 39*38/2
#define NPAD   752      // 47 tiles * 16
#define DIM    64
#define NTILES 47
#define ESTRH  72       // padded fp16 row stride (halves): 36 dwords -> bank-spread

typedef float    f32x4 __attribute__((ext_vector_type(4)));
typedef _Float16 f16x8 __attribute__((ext_vector_type(8)));

union H8 {
    f16x8    v;
    __half2  h2[4];
    _Float16 h[8];
};

__global__ __launch_bounds__(256, 3) void afm_mfma2(
    const int*   __restrict__ feat_index,   // [B, F]
    const float* __restrict__ feat_value,   // [B, F]
    const float* __restrict__ fo_w,         // [NUM_FEATS, 1]
    const float* __restrict__ emb_table,    // [NUM_FEATS, 64]
    const float* __restrict__ att_W,        // [64, 64] (d, a)
    const float* __restrict__ att_b,        // [64]
    const float* __restrict__ att_h,        // [64]
    const float* __restrict__ p_vec,        // [64]
    const float* __restrict__ bias,         // [1]
    float*       __restrict__ out)          // [B]
{
    const int b    = blockIdx.x;
    const int t    = threadIdx.x;
    const int wave = t >> 6;
    const int lane = t & 63;
    const int la   = lane & 15;   // pair-within-tile (B col / C col)
    const int lg   = lane >> 4;   // k-group / C row-group

    __shared__ __half         e_lds[NUM_F][ESTRH];  // scaled embeddings, fp16
    __shared__ __half         Wt[DIM][ESTRH];       // W^T fp16: Wt[a][d]
    __shared__ float          sig_s[NPAD];
    __shared__ float          q_s[NPAD];
    __shared__ float          b_lds[DIM], h_lds[DIM], pv_lds[DIM];
    __shared__ unsigned short pairRC[NPAD];         // (r<<8)|c
    __shared__ int            s_idx[NUM_F];
    __shared__ float          s_fv[NUM_F];
    __shared__ float          s_yfirst;
    __shared__ float          wred[12];             // wave partials: max, S, Q

    // ---------------- phase 0: staging ----------------
    int   my_idx = 0;
    float my_fv  = 0.f;
    if (t < NUM_F) {
        my_idx   = feat_index[b * NUM_F + t];
        my_fv    = feat_value[b * NUM_F + t];
        s_idx[t] = my_idx;
        s_fv[t]  = my_fv;
    }
    if (t < DIM) {
        b_lds[t]  = att_b[t];
        h_lds[t]  = att_h[t];
        pv_lds[t] = p_vec[t];
    }
    if (t < NUM_F) {   // triu(k=1) pair map, row-major
        int r = t, off = r * (2 * NUM_F - r - 1) / 2;
        for (int c = r + 1; c < NUM_F; ++c) {
            pairRC[off] = (unsigned short)((r << 8) | c);
            ++off;
        }
    }
    if (t < NPAD - NUM_P) pairRC[NUM_P + t] = 0;

    // W^T -> fp16 LDS (coalesced reads, scattered u16 writes, once per block)
    for (int q = t; q < DIM * DIM; q += 256) {
        int d = q >> 6, a = q & 63;
        Wt[a][d] = (__half)(_Float16)att_W[q];
    }

    // y_first: wave 0 butterfly
    float yf = (t < NUM_F) ? fo_w[my_idx] * my_fv : 0.f;
    if (wave == 0) {
        #pragma unroll
        for (int m = 1; m < 64; m <<= 1) yf += __shfl_xor(yf, m);
        if (t == 0) s_yfirst = yf;
    }
    __syncthreads();

    // ---------------- phase 1: E staging (fp16) ----------------
    {
        const float4* emb4 = (const float4*)emb_table;
        for (int q = t; q < NUM_F * 8; q += 256) {
            int f = q >> 3, d8 = q & 7;
            float4 v0 = emb4[(size_t)s_idx[f] * 16 + d8 * 2];
            float4 v1 = emb4[(size_t)s_idx[f] * 16 + d8 * 2 + 1];
            float fv = s_fv[f];
            H8 hh;
            hh.h2[0] = __float22half2_rn(make_float2(v0.x * fv, v0.y * fv));
            hh.h2[1] = __float22half2_rn(make_float2(v0.z * fv, v0.w * fv));
            hh.h2[2] = __float22half2_rn(make_float2(v1.x * fv, v1.y * fv));
            hh.h2[3] = __float22half2_rn(make_float2(v1.z * fv, v1.w * fv));
            *(f16x8*)&e_lds[f][d8 * 8] = hh.v;
        }
    }
    __syncthreads();

    // ---------------- hoisted stationary fragments ----------------
    // A-frags = W^T tiles: lane holds row a = n*16+la, k(d) = kf*32 + lg*8 + j
    f16x8 WA[4][2];
    #pragma unroll
    for (int n = 0; n < 4; ++n)
        #pragma unroll
        for (int kf = 0; kf < 2; ++kf)
            WA[n][kf] = *(const f16x8*)&Wt[n * 16 + la][kf * 32 + lg * 8];

    // p_vec as row 0 of a 5th A-tile
    f16x8 PA[2];
    #pragma unroll
    for (int kf = 0; kf < 2; ++kf) {
        H8 P;
        #pragma unroll
        for (int j = 0; j < 8; ++j) {
            float x = (la == 0) ? pv_lds[kf * 32 + lg * 8 + j] : 0.f;
            P.h[j] = (_Float16)x;
        }
        PA[kf] = P.v;
    }

    // bias (accum init) and h, per lane's C rows: a = n*16 + lg*4 + i
    f32x4 b4[4], h4[4];
    #pragma unroll
    for (int n = 0; n < 4; ++n) {
        b4[n] = *(const f32x4*)&b_lds[n * 16 + lg * 4];
        h4[n] = *(const f32x4*)&h_lds[n * 16 + lg * 4];
    }

    // ---------------- phase 2: pair-tile loop (16 pairs / tile / wave) ----------------
    #pragma unroll 1
    for (int tile = wave; tile < NTILES; tile += 4) {
        const int p0 = tile << 4;
        const int p  = p0 + la;
        const unsigned int rc = pairRC[p];
        const int r = rc >> 8;
        const int c = rc & 255;

        // B-frags = inter: col = la (pair), k(d) = kf*32 + lg*8 + j
        H8 er0, er1, ec0, ec1, B0, B1;
        er0.v = *(const f16x8*)&e_lds[r][lg * 8];
        er1.v = *(const f16x8*)&e_lds[r][32 + lg * 8];
        ec0.v = *(const f16x8*)&e_lds[c][lg * 8];
        ec1.v = *(const f16x8*)&e_lds[c][32 + lg * 8];
        #pragma unroll
        for (int i = 0; i < 4; ++i) {
            B0.h2[i] = __hmul2(er0.h2[i], ec0.h2[i]);
            B1.h2[i] = __hmul2(er1.h2[i], ec1.h2[i]);
        }

        // Z^T tiles: D[a][pair], bias folded into init
        f32x4 a0 = b4[0], a1 = b4[1], a2 = b4[2], a3 = b4[3];
        f32x4 aq = {0.f, 0.f, 0.f, 0.f};

        a0 = __builtin_amdgcn_mfma_f32_16x16x32_f16(WA[0][0], B0.v, a0, 0, 0, 0);
        a1 = __builtin_amdgcn_mfma_f32_16x16x32_f16(WA[1][0], B0.v, a1, 0, 0, 0);
        a2 = __builtin_amdgcn_mfma_f32_16x16x32_f16(WA[2][0], B0.v, a2, 0, 0, 0);
        a3 = __builtin_amdgcn_mfma_f32_16x16x32_f16(WA[3][0], B0.v, a3, 0, 0, 0);
        aq = __builtin_amdgcn_mfma_f32_16x16x32_f16(PA[0],    B0.v, aq, 0, 0, 0);
        a0 = __builtin_amdgcn_mfma_f32_16x16x32_f16(WA[0][1], B1.v, a0, 0, 0, 0);
        a1 = __builtin_amdgcn_mfma_f32_16x16x32_f16(WA[1][1], B1.v, a1, 0, 0, 0);
        a2 = __builtin_amdgcn_mfma_f32_16x16x32_f16(WA[2][1], B1.v, a2, 0, 0, 0);
        a3 = __builtin_amdgcn_mfma_f32_16x16x32_f16(WA[3][1], B1.v, a3, 0, 0, 0);
        aq = __builtin_amdgcn_mfma_f32_16x16x32_f16(PA[1],    B1.v, aq, 0, 0, 0);

        // epilogue: sig[pair] = sum_a relu(Zt[a][pair]) * h[a]
        // lane (la,lg) holds a = n*16 + lg*4 + i  ->  local 16 terms, reduce over lg
        float s;
        {
            float t0 = fmaxf(a0[0], 0.f) * h4[0][0];
            t0 = fmaf(fmaxf(a0[1], 0.f), h4[0][1], t0);
            t0 = fmaf(fmaxf(a0[2], 0.f), h4[0][2], t0);
            t0 = fmaf(fmaxf(a0[3], 0.f), h4[0][3], t0);
            t0 = fmaf(fmaxf(a1[0], 0.f), h4[1][0], t0);
            t0 = fmaf(fmaxf(a1[1], 0.f), h4[1][1], t0);
            t0 = fmaf(fmaxf(a1[2], 0.f), h4[1][2], t0);
            t0 = fmaf(fmaxf(a1[3], 0.f), h4[1][3], t0);
            t0 = fmaf(fmaxf(a2[0], 0.f), h4[2][0], t0);
            t0 = fmaf(fmaxf(a2[1], 0.f), h4[2][1], t0);
            t0 = fmaf(fmaxf(a2[2], 0.f), h4[2][2], t0);
            t0 = fmaf(fmaxf(a2[3], 0.f), h4[2][3], t0);
            t0 = fmaf(fmaxf(a3[0], 0.f), h4[3][0], t0);
            t0 = fmaf(fmaxf(a3[1], 0.f), h4[3][1], t0);
            t0 = fmaf(fmaxf(a3[2], 0.f), h4[3][2], t0);
            t0 = fmaf(fmaxf(a3[3], 0.f), h4[3][3], t0);
            t0 += __shfl_xor(t0, 16);
            t0 += __shfl_xor(t0, 32);
            s = t0;
        }

        if (lg == 0 && p < NUM_P) {
            sig_s[p] = s;
            q_s[p]   = aq[0];   // q at C row 0 = (lg==0, reg 0)
        }
    }
    __syncthreads();

    // ---------------- phase 3: softmax + pooling (wave reductions) ----------------
    float sv[3], qv[3];
    #pragma unroll
    for (int i = 0; i < 3; ++i) {
        int p = t + i * 256;
        bool ok = p < NUM_P;
        sv[i] = ok ? sig_s[p] : -1e30f;
        qv[i] = ok ? q_s[p]   : 0.f;
    }

    float m3 = fmaxf(fmaxf(sv[0], sv[1]), sv[2]);
    #pragma unroll
    for (int mm = 1; mm < 64; mm <<= 1) m3 = fmaxf(m3, __shfl_xor(m3, mm));
    if (lane == 0) wred[wave] = m3;
    __syncthreads();
    const float M = fmaxf(fmaxf(wred[0], wred[1]), fmaxf(wred[2], wred[3]));

    float S = 0.f, Q = 0.f;
    #pragma unroll
    for (int i = 0; i < 3; ++i) {
        float eo = __expf(sv[i] - M);
        S += eo;
        Q += eo * qv[i];
    }
    #pragma unroll
    for (int mm = 1; mm < 64; mm <<= 1) {
        S += __shfl_xor(S, mm);
        Q += __shfl_xor(Q, mm);
    }
    if (lane == 0) { wred[4 + wave] = S; wred[8 + wave] = Q; }
    __syncthreads();

    if (t == 0) {
        const float Ssum = wred[4] + wred[5] + wred[6] + wred[7];
        const float Qsum = wred[8] + wred[9] + wred[10] + wred[11];
        const float att_pool = Qsum / Ssum;
        const float x = bias[0] + s_yfirst + att_pool;
        out[b] = 1.f / (1.f + __expf(-x));
    }
}

extern "C" void kernel_launch(void* const* d_in, const int* in_sizes, int n_in,
                              void* d_out, int out_size, void* d_ws, size_t ws_size,
                              hipStream_t stream) {
    const int*   feat_index = (const int*)  d_in[0];
    const float* feat_value = (const float*)d_in[1];
    const float* fo_w       = (const float*)d_in[2];
    const float* emb_table  = (const float*)d_in[3];
    const float* att_W      = (const float*)d_in[4];
    const float* att_b      = (const float*)d_in[5];
    const float* att_h      = (const float*)d_in[6];
    const float* p_vec      = (const float*)d_in[7];
    const float* bias       = (const float*)d_in[8];
    float*       out        = (float*)d_out;

    const int B = in_sizes[0] / NUM_F;   // 2048

    afm_mfma2<<<B, 256, 0, stream>>>(feat_index, feat_value, fo_w, emb_table,
                                     att_W, att_b, att_h, p_vec, bias, out);
}